// Round 1
// baseline (54961.823 us; speedup 1.0000x reference)
//
#include <hip/hip_runtime.h>
#include <hip/hip_cooperative_groups.h>
#include <math.h>

namespace cg = cooperative_groups;

#define BB 32      // batch
#define SS 64      // source length
#define HH 1024    // hidden
#define VV 32000   // vocab
#define NSTEPS 64  // decode steps
#define GRID 256   // cooperative grid: 1 block/CU

__device__ __forceinline__ float sigmoidf_(float x) { return 1.0f / (1.0f + expf(-x)); }

// ==================================================================
// Cooperative mega-kernel: whole encoder + hs_a + whole decoder in ONE
// launch. Phases separated by grid.sync(); inner loops identical to the
// verified multi-kernel version (same FP order -> same results).
// ==================================================================

struct MegaP {
    const int* source; const float* emb_enc;
    const float* Wx_e; const float* Wh_e; const float* b_e;
    const float* emb_dec; const float* Wx_d; const float* Wh_d; const float* b_d;
    const float* W_a; const float* W_c; const float* b_c;
    const float* W_out; const float* b_out;
    float* out;
    float* h; float* c; float* hs; float* hs_a; float* ctx; float* ht;
    float* zpart; float* wcpart; int* y;
};

union SharedU {
    float At[256][36];                                    // GEMM A-staging (max KS=256): 36 KB
    float hsaAt[64][12];                                  // hs_a staging
    struct { float h2s[HH]; float red[256]; float av[SS]; } a;  // attention
    struct { float rv[256]; int ri[256]; float rs[256]; } s;    // vocab softmax
};

// skinny GEMM tile: out[ks][b][n] = sum_{k in slice ks} A[b][k] * W[k][n]
// A row = [A1row (1024) | A2row (1024)]; A1 direct or emb[tok[b]] gather.
template <int KS>
__device__ void gemm_tile(
    const float* __restrict__ A1, const float* __restrict__ A2,
    const int* __restrict__ tok, int tok_stride, const float* __restrict__ emb,
    const float* __restrict__ W1, const float* __restrict__ W2, int KW1,
    int N, int jblocks, int tile, float* __restrict__ outp, float (*At)[36])
{
    const int tid = threadIdx.x;
    const int jb = tile % jblocks;
    const int ks = tile / jblocks;
    const int k0 = ks * KS;

    __syncthreads();  // LDS reuse guard (multi-tile loops)
    for (int i = tid; i < KS * BB; i += 256) {
        int b = i / KS;
        int k = i % KS;
        int kg = k0 + k;
        float v;
        if (kg < 1024) {
            const float* r = A1 ? (A1 + (size_t)b * 1024)
                                : (emb + (size_t)tok[b * tok_stride] * 1024);
            v = r[kg];
        } else {
            v = A2[(size_t)b * 1024 + (kg - 1024)];
        }
        At[k][b] = v;
    }
    __syncthreads();

    const int jj = jb * 256 + tid;
    if (2 * jj < N) {
        const float* Wbase = (k0 < KW1) ? (W1 + (size_t)k0 * N)
                                        : (W2 + (size_t)(k0 - KW1) * N);
        float2 acc[BB];
#pragma unroll
        for (int b = 0; b < BB; b++) { acc[b].x = 0.f; acc[b].y = 0.f; }

#pragma unroll 4   // 4 W-loads in flight: cover L3 latency at 1 wave/SIMD
        for (int k = 0; k < KS; k++) {
            const float2 w = *(const float2*)(Wbase + (size_t)k * N + 2 * jj);
#pragma unroll
            for (int b = 0; b < BB; b += 4) {
                const float4 a = *(const float4*)&At[k][b];  // uniform-addr LDS broadcast
                acc[b + 0].x = fmaf(a.x, w.x, acc[b + 0].x); acc[b + 0].y = fmaf(a.x, w.y, acc[b + 0].y);
                acc[b + 1].x = fmaf(a.y, w.x, acc[b + 1].x); acc[b + 1].y = fmaf(a.y, w.y, acc[b + 1].y);
                acc[b + 2].x = fmaf(a.z, w.x, acc[b + 2].x); acc[b + 2].y = fmaf(a.z, w.y, acc[b + 2].y);
                acc[b + 3].x = fmaf(a.w, w.x, acc[b + 3].x); acc[b + 3].y = fmaf(a.w, w.y, acc[b + 3].y);
            }
        }
#pragma unroll
        for (int b = 0; b < BB; b++) {
            *(float2*)(outp + ((size_t)ks * BB + b) * N + 2 * jj) = acc[b];
        }
    }
}

__device__ void hsa_tile(const float* __restrict__ hs, const float* __restrict__ W_a,
                         float* __restrict__ hs_a, int tile, float (*At)[12])
{
    const int tid = threadIdx.x;
    const int rg = tile & 255;   // rowgroup of 8 rows
    const int jpb = tile >> 8;   // 0..1
    const int jj = jpb * 256 + tid;
    float2 acc[8];
#pragma unroll
    for (int r = 0; r < 8; r++) { acc[r].x = 0.f; acc[r].y = 0.f; }

    for (int kc = 0; kc < 1024; kc += 64) {
        __syncthreads();
        for (int i = tid; i < 512; i += 256) {
            int r = i >> 6, k = i & 63;
            At[k][r] = hs[(size_t)(rg * 8 + r) * 1024 + kc + k];
        }
        __syncthreads();
#pragma unroll 1
        for (int k = 0; k < 64; k++) {
            float2 w = *(const float2*)(W_a + (size_t)(kc + k) * 1024 + 2 * jj);
            float4 a0 = *(const float4*)&At[k][0];
            float4 a1 = *(const float4*)&At[k][4];
            acc[0].x = fmaf(a0.x, w.x, acc[0].x); acc[0].y = fmaf(a0.x, w.y, acc[0].y);
            acc[1].x = fmaf(a0.y, w.x, acc[1].x); acc[1].y = fmaf(a0.y, w.y, acc[1].y);
            acc[2].x = fmaf(a0.z, w.x, acc[2].x); acc[2].y = fmaf(a0.z, w.y, acc[2].y);
            acc[3].x = fmaf(a0.w, w.x, acc[3].x); acc[3].y = fmaf(a0.w, w.y, acc[3].y);
            acc[4].x = fmaf(a1.x, w.x, acc[4].x); acc[4].y = fmaf(a1.x, w.y, acc[4].y);
            acc[5].x = fmaf(a1.y, w.x, acc[5].x); acc[5].y = fmaf(a1.y, w.y, acc[5].y);
            acc[6].x = fmaf(a1.z, w.x, acc[6].x); acc[6].y = fmaf(a1.z, w.y, acc[6].y);
            acc[7].x = fmaf(a1.w, w.x, acc[7].x); acc[7].y = fmaf(a1.w, w.y, acc[7].y);
        }
    }
#pragma unroll
    for (int r = 0; r < 8; r++)
        *(float2*)(hs_a + (size_t)(rg * 8 + r) * 1024 + 2 * jj) = acc[r];
}

// gates + mask + attention for one batch row b (block-local)
__device__ void attn_phase(const MegaP& p, int b, SharedU& sh)
{
    const int tid = threadIdx.x;
    const bool m = (p.y[b] != 0);

    for (int u = 0; u < 4; u++) {
        int j = tid + 256 * u;
        float zi = p.b_d[j], zf = p.b_d[1024 + j], zg = p.b_d[2048 + j], zo = p.b_d[3072 + j];
        for (int ks = 0; ks < 32; ks++) {
            const float* zp = p.zpart + ((size_t)ks * BB + b) * 4096;
            zi += zp[j]; zf += zp[1024 + j]; zg += zp[2048 + j]; zo += zp[3072 + j];
        }
        int idx = b * HH + j;
        float cp = p.c[idx], hp = p.h[idx];
        float c2 = sigmoidf_(zf) * cp + sigmoidf_(zi) * tanhf(zg);
        float h2 = sigmoidf_(zo) * tanhf(c2);
        if (!m) { c2 = cp; h2 = hp; }
        p.c[idx] = c2; p.h[idx] = h2; sh.a.h2s[j] = h2;
    }
    __syncthreads();

    {   // scores: 64 t-lanes x 4 k-chunks of 256
        int t = tid & 63, kc = tid >> 6;
        const float4* row = (const float4*)(p.hs_a + ((size_t)b * SS + t) * HH) + kc * 64;
        const float4* hv = (const float4*)sh.a.h2s + kc * 64;
        float sc = 0.f;
#pragma unroll 4
        for (int i = 0; i < 64; i++) {
            float4 a = row[i], x = hv[i];
            sc += a.x * x.x + a.y * x.y + a.z * x.z + a.w * x.w;
        }
        sh.a.red[tid] = sc;
    }
    __syncthreads();
    if (tid < 64) {
        float s = sh.a.red[tid] + sh.a.red[tid + 64] + sh.a.red[tid + 128] + sh.a.red[tid + 192];
        if (p.source[b * SS + tid] == 0) s = -1e9f;
        sh.a.red[tid] = s;
    }
    __syncthreads();
    if (tid < 64) {
        float mx = -3.4e38f;
        for (int i = 0; i < 64; i++) mx = fmaxf(mx, sh.a.red[i]);
        sh.a.av[tid] = expf(sh.a.red[tid] - mx);
    }
    __syncthreads();
    if (tid < 64) {  // single wave: loads precede store in program order
        float ssum = 0.f;
        for (int i = 0; i < 64; i++) ssum += sh.a.av[i];
        sh.a.av[tid] = sh.a.av[tid] / ssum;
    }
    __syncthreads();
    for (int u = 0; u < 4; u++) {
        int j = tid + 256 * u;
        float s = 0.f;
        for (int t2 = 0; t2 < SS; t2++) s += sh.a.av[t2] * p.hs[((size_t)b * SS + t2) * HH + j];
        p.ctx[b * HH + j] = s;
    }
}

// vocab softmax + argmax for one batch row b (block-local)
__device__ void softmax_phase(const MegaP& p, int b, int step, SharedU& sh)
{
    const int tid = threadIdx.x;
    const float* lpart = p.zpart;   // aliases zpart (4 slices x B x V)
    float* lrow = p.wcpart;         // aliases wcpart (B x V)

    float bmax = -3.4e38f; int barg = 0;
    for (int v = tid; v < VV; v += 256) {
        float l = p.b_out[v];
        l += lpart[((size_t)0 * BB + b) * VV + v];
        l += lpart[((size_t)1 * BB + b) * VV + v];
        l += lpart[((size_t)2 * BB + b) * VV + v];
        l += lpart[((size_t)3 * BB + b) * VV + v];
        lrow[(size_t)b * VV + v] = l;
        if (l > bmax) { bmax = l; barg = v; }  // strict > keeps lowest index per thread
    }
    sh.s.rv[tid] = bmax; sh.s.ri[tid] = barg;
    __syncthreads();
    for (int off = 128; off > 0; off >>= 1) {
        if (tid < off) {
            float v2 = sh.s.rv[tid + off]; int i2 = sh.s.ri[tid + off];
            if (v2 > sh.s.rv[tid] || (v2 == sh.s.rv[tid] && i2 < sh.s.ri[tid])) {
                sh.s.rv[tid] = v2; sh.s.ri[tid] = i2;
            }
        }
        __syncthreads();
    }
    const float mx = sh.s.rv[0];
    float ls = 0.f;
    for (int v = tid; v < VV; v += 256) ls += expf(lrow[(size_t)b * VV + v] - mx);
    sh.s.rs[tid] = ls;
    __syncthreads();
    for (int off = 128; off > 0; off >>= 1) {
        if (tid < off) sh.s.rs[tid] += sh.s.rs[tid + off];
        __syncthreads();
    }
    const float inv = 1.0f / sh.s.rs[0];
    float* orow = p.out + ((size_t)b * NSTEPS + step) * VV;
    for (int v = tid; v < VV; v += 256) orow[v] = expf(lrow[(size_t)b * VV + v] - mx) * inv;
    if (tid == 0) p.y[b] = sh.s.ri[0];
}

__global__ __launch_bounds__(256) void mega(MegaP p)
{
    cg::grid_group grid = cg::this_grid();
    __shared__ SharedU sh;
    const int bid = blockIdx.x;
    const int tid = threadIdx.x;
    const int gidx = bid * 256 + tid;

    // ---- phase 0: init h,c = 0, y = BOS ----
    if (gidx < BB * HH) { p.h[gidx] = 0.f; p.c[gidx] = 0.f; }
    if (gidx < BB) p.y[gidx] = 1;
    grid.sync();

    // ---- encoder: 64 steps ----
    for (int s = 0; s < SS; s++) {
        // z = [emb_enc[src[:,s]] ; h] @ [Wx_e ; Wh_e]: 32 k-slices x 8 jb = 256 tiles
        gemm_tile<64>(nullptr, p.h, p.source + s, SS, p.emb_enc,
                      p.Wx_e, p.Wh_e, 1024, 4096, 8, bid, p.zpart, sh.At);
        grid.sync();
        if (gidx < BB * HH) {  // gates
            int b = gidx >> 10, j = gidx & 1023;
            float zi = p.b_e[j], zf = p.b_e[1024 + j], zg = p.b_e[2048 + j], zo = p.b_e[3072 + j];
            for (int ks = 0; ks < 32; ks++) {
                const float* zp = p.zpart + ((size_t)ks * BB + b) * 4096;
                zi += zp[j]; zf += zp[1024 + j]; zg += zp[2048 + j]; zo += zp[3072 + j];
            }
            float cp = p.c[gidx];
            float c2 = sigmoidf_(zf) * cp + sigmoidf_(zi) * tanhf(zg);
            float h2 = sigmoidf_(zo) * tanhf(c2);
            p.c[gidx] = c2; p.h[gidx] = h2;
            p.hs[((size_t)b * SS + s) * HH + j] = h2;
        }
        grid.sync();
    }

    // ---- hs_a = hs @ W_a: 512 tiles, 2 per block ----
    for (int tile = bid; tile < 512; tile += GRID)
        hsa_tile(p.hs, p.W_a, p.hs_a, tile, sh.hsaAt);
    grid.sync();

    // ---- decoder: 64 steps ----
    for (int t = 0; t < NSTEPS; t++) {
        // P1: z = [emb_dec[y] ; h] @ [Wx_d ; Wh_d]: 256 tiles
        gemm_tile<64>(nullptr, p.h, p.y, 1, p.emb_dec,
                      p.Wx_d, p.Wh_d, 1024, 4096, 8, bid, p.zpart, sh.At);
        grid.sync();
        // P2: gates + mask + attention, one block per b
        if (bid < BB) attn_phase(p, bid, sh);
        grid.sync();
        // P3: wcpart = [ctx ; h2] @ W_c: 64 k-slices of 32 x 2 jb = 128 tiles
        if (bid < 128) gemm_tile<32>(p.ctx, p.h, nullptr, 0, nullptr,
                                     p.W_c, nullptr, 2048, 1024, 2, bid, p.wcpart, sh.At);
        grid.sync();
        // P4: ht = tanh(reduce(wcpart) + b_c)
        if (gidx < BB * HH) {
            int b = gidx >> 10, j = gidx & 1023;
            float sum = p.b_c[j];
            for (int ks = 0; ks < 64; ks++) sum += p.wcpart[((size_t)ks * BB + b) * HH + j];
            p.ht[gidx] = tanhf(sum);
        }
        grid.sync();
        // P5: logits partials = ht @ W_out: 4 k-slices of 256 x 63 jb = 252 tiles
        if (bid < 252) gemm_tile<256>(p.ht, nullptr, nullptr, 0, nullptr,
                                      p.W_out, nullptr, 1024, 32000, 63, bid, p.zpart, sh.At);
        grid.sync();
        // P6: softmax over V + argmax -> y, one block per b
        if (bid < BB) softmax_phase(p, bid, t, sh);
        grid.sync();
    }
}

// ==================================================================
// Fallback path: the proven multi-kernel version (unchanged), used only
// if the cooperative launch is rejected.
// ==================================================================

__global__ void init_hc(float* __restrict__ h, float* __restrict__ c) {
    int i = blockIdx.x * 256 + threadIdx.x;
    if (i < BB * HH) { h[i] = 0.f; c[i] = 0.f; }
}

template <int KS>
__global__ __launch_bounds__(256) void gemm_skinny(
    const float* __restrict__ A1, const float* __restrict__ A2,
    const int* __restrict__ tok, int tok_stride, const float* __restrict__ emb,
    const float* __restrict__ W1, const float* __restrict__ W2, int KW1,
    int N, int jblocks, float* __restrict__ outp)
{
    __shared__ alignas(16) float At[KS][36];
    const int tid = threadIdx.x;
    const int jb = blockIdx.x % jblocks;
    const int ks = blockIdx.x / jblocks;
    const int k0 = ks * KS;

    for (int i = tid; i < KS * BB; i += 256) {
        int b = i / KS;
        int k = i % KS;
        int kg = k0 + k;
        float v;
        if (kg < 1024) {
            const float* r = A1 ? (A1 + (size_t)b * 1024)
                                : (emb + (size_t)tok[b * tok_stride] * 1024);
            v = r[kg];
        } else {
            v = A2[(size_t)b * 1024 + (kg - 1024)];
        }
        At[k][b] = v;
    }
    __syncthreads();

    const int jj = jb * 256 + tid;
    if (2 * jj >= N) return;
    const float* Wbase = (k0 < KW1) ? (W1 + (size_t)k0 * N)
                                    : (W2 + (size_t)(k0 - KW1) * N);
    float2 acc[BB];
#pragma unroll
    for (int b = 0; b < BB; b++) { acc[b].x = 0.f; acc[b].y = 0.f; }

#pragma unroll 1
    for (int k = 0; k < KS; k++) {
        const float2 w = *(const float2*)(Wbase + (size_t)k * N + 2 * jj);
#pragma unroll
        for (int b = 0; b < BB; b += 4) {
            const float4 a = *(const float4*)&At[k][b];
            acc[b + 0].x = fmaf(a.x, w.x, acc[b + 0].x); acc[b + 0].y = fmaf(a.x, w.y, acc[b + 0].y);
            acc[b + 1].x = fmaf(a.y, w.x, acc[b + 1].x); acc[b + 1].y = fmaf(a.y, w.y, acc[b + 1].y);
            acc[b + 2].x = fmaf(a.z, w.x, acc[b + 2].x); acc[b + 2].y = fmaf(a.z, w.y, acc[b + 2].y);
            acc[b + 3].x = fmaf(a.w, w.x, acc[b + 3].x); acc[b + 3].y = fmaf(a.w, w.y, acc[b + 3].y);
        }
    }
#pragma unroll
    for (int b = 0; b < BB; b++) {
        *(float2*)(outp + ((size_t)ks * BB + b) * N + 2 * jj) = acc[b];
    }
}

__global__ __launch_bounds__(256) void enc_gates(
    const float* __restrict__ zpart, int nslices, const float* __restrict__ bias,
    float* __restrict__ h, float* __restrict__ c, float* __restrict__ hs, int s)
{
    int idx = blockIdx.x * 256 + threadIdx.x;
    int b = idx >> 10, j = idx & 1023;
    float zi = bias[j], zf = bias[1024 + j], zg = bias[2048 + j], zo = bias[3072 + j];
    for (int ks = 0; ks < nslices; ks++) {
        const float* zp = zpart + ((size_t)ks * BB + b) * 4096;
        zi += zp[j]; zf += zp[1024 + j]; zg += zp[2048 + j]; zo += zp[3072 + j];
    }
    float cp = c[idx];
    float c2 = sigmoidf_(zf) * cp + sigmoidf_(zi) * tanhf(zg);
    float h2 = sigmoidf_(zo) * tanhf(c2);
    c[idx] = c2; h[idx] = h2;
    hs[((size_t)b * SS + s) * HH + j] = h2;
}

__global__ __launch_bounds__(256) void hsa_kernel(
    const float* __restrict__ hs, const float* __restrict__ W_a,
    float* __restrict__ hs_a, int* __restrict__ y)
{
    if (blockIdx.x == 0 && threadIdx.x < BB) y[threadIdx.x] = 1;
    __shared__ alignas(16) float At[64][12];
    const int tid = threadIdx.x;
    const int rg = blockIdx.x & 255;
    const int jpb = blockIdx.x >> 8;
    const int jj = jpb * 256 + tid;
    float2 acc[8];
#pragma unroll
    for (int r = 0; r < 8; r++) { acc[r].x = 0.f; acc[r].y = 0.f; }

    for (int kc = 0; kc < 1024; kc += 64) {
        __syncthreads();
        for (int i = tid; i < 512; i += 256) {
            int r = i >> 6, k = i & 63;
            At[k][r] = hs[(size_t)(rg * 8 + r) * 1024 + kc + k];
        }
        __syncthreads();
#pragma unroll 1
        for (int k = 0; k < 64; k++) {
            float2 w = *(const float2*)(W_a + (size_t)(kc + k) * 1024 + 2 * jj);
            float4 a0 = *(const float4*)&At[k][0];
            float4 a1 = *(const float4*)&At[k][4];
            acc[0].x = fmaf(a0.x, w.x, acc[0].x); acc[0].y = fmaf(a0.x, w.y, acc[0].y);
            acc[1].x = fmaf(a0.y, w.x, acc[1].x); acc[1].y = fmaf(a0.y, w.y, acc[1].y);
            acc[2].x = fmaf(a0.z, w.x, acc[2].x); acc[2].y = fmaf(a0.z, w.y, acc[2].y);
            acc[3].x = fmaf(a0.w, w.x, acc[3].x); acc[3].y = fmaf(a0.w, w.y, acc[3].y);
            acc[4].x = fmaf(a1.x, w.x, acc[4].x); acc[4].y = fmaf(a1.x, w.y, acc[4].y);
            acc[5].x = fmaf(a1.y, w.x, acc[5].x); acc[5].y = fmaf(a1.y, w.y, acc[5].y);
            acc[6].x = fmaf(a1.z, w.x, acc[6].x); acc[6].y = fmaf(a1.z, w.y, acc[6].y);
            acc[7].x = fmaf(a1.w, w.x, acc[7].x); acc[7].y = fmaf(a1.w, w.y, acc[7].y);
        }
    }
#pragma unroll
    for (int r = 0; r < 8; r++)
        *(float2*)(hs_a + (size_t)(rg * 8 + r) * 1024 + 2 * jj) = acc[r];
}

__global__ __launch_bounds__(256) void attn_gates(
    const float* __restrict__ zpart, int nslices, const float* __restrict__ bias,
    const int* __restrict__ y, float* __restrict__ h, float* __restrict__ c,
    const float* __restrict__ hs_a, const float* __restrict__ hs,
    const int* __restrict__ source, float* __restrict__ ctx)
{
    __shared__ alignas(16) float h2s[HH];
    __shared__ float red[256];
    __shared__ float av[SS];
    const int b = blockIdx.x, tid = threadIdx.x;
    const bool m = (y[b] != 0);

    for (int u = 0; u < 4; u++) {
        int j = tid + 256 * u;
        float zi = bias[j], zf = bias[1024 + j], zg = bias[2048 + j], zo = bias[3072 + j];
        for (int ks = 0; ks < nslices; ks++) {
            const float* zp = zpart + ((size_t)ks * BB + b) * 4096;
            zi += zp[j]; zf += zp[1024 + j]; zg += zp[2048 + j]; zo += zp[3072 + j];
        }
        int idx = b * HH + j;
        float cp = c[idx], hp = h[idx];
        float c2 = sigmoidf_(zf) * cp + sigmoidf_(zi) * tanhf(zg);
        float h2 = sigmoidf_(zo) * tanhf(c2);
        if (!m) { c2 = cp; h2 = hp; }
        c[idx] = c2; h[idx] = h2; h2s[j] = h2;
    }
    __syncthreads();

    {
        int t = tid & 63, kc = tid >> 6;
        const float4* row = (const float4*)(hs_a + ((size_t)b * SS + t) * HH) + kc * 64;
        const float4* hv = (const float4*)h2s + kc * 64;
        float sc = 0.f;
#pragma unroll 4
        for (int i = 0; i < 64; i++) {
            float4 a = row[i], x = hv[i];
            sc += a.x * x.x + a.y * x.y + a.z * x.z + a.w * x.w;
        }
        red[tid] = sc;
    }
    __syncthreads();
    if (tid < 64) {
        float s = red[tid] + red[tid + 64] + red[tid + 128] + red[tid + 192];
        if (source[b * SS + tid] == 0) s = -1e9f;
        red[tid] = s;
    }
    __syncthreads();
    if (tid < 64) {
        float mx = -3.4e38f;
        for (int i = 0; i < 64; i++) mx = fmaxf(mx, red[i]);
        av[tid] = expf(red[tid] - mx);
    }
    __syncthreads();
    if (tid < 64) {
        float ssum = 0.f;
        for (int i = 0; i < 64; i++) ssum += av[i];
        av[tid] = av[tid] / ssum;
    }
    __syncthreads();
    for (int u = 0; u < 4; u++) {
        int j = tid + 256 * u;
        float s = 0.f;
        for (int t = 0; t < SS; t++) s += av[t] * hs[((size_t)b * SS + t) * HH + j];
        ctx[b * HH + j] = s;
    }
}

__global__ __launch_bounds__(256) void ht_reduce(
    const float* __restrict__ wcpart, int nslices,
    const float* __restrict__ b_c, float* __restrict__ ht)
{
    int idx = blockIdx.x * 256 + threadIdx.x;
    int b = idx >> 10, j = idx & 1023;
    float s = b_c[j];
    for (int ks = 0; ks < nslices; ks++) s += wcpart[((size_t)ks * BB + b) * HH + j];
    ht[idx] = tanhf(s);
}

__global__ __launch_bounds__(256) void softmax_out(
    const float* __restrict__ lpart,
    const float* __restrict__ b_out, float* __restrict__ lrow,
    float* __restrict__ out, int* __restrict__ y, int step)
{
    __shared__ float rv[256];
    __shared__ int ri[256];
    __shared__ float rs[256];
    const int b = blockIdx.x, tid = threadIdx.x;
    float bmax = -3.4e38f; int barg = 0;
    for (int v = tid; v < VV; v += 256) {
        float l = b_out[v];
        l += lpart[((size_t)0 * BB + b) * VV + v];
        l += lpart[((size_t)1 * BB + b) * VV + v];
        l += lpart[((size_t)2 * BB + b) * VV + v];
        l += lpart[((size_t)3 * BB + b) * VV + v];
        lrow[(size_t)b * VV + v] = l;
        if (l > bmax) { bmax = l; barg = v; }
    }
    rv[tid] = bmax; ri[tid] = barg;
    __syncthreads();
    for (int off = 128; off > 0; off >>= 1) {
        if (tid < off) {
            float v2 = rv[tid + off]; int i2 = ri[tid + off];
            if (v2 > rv[tid] || (v2 == rv[tid] && i2 < ri[tid])) { rv[tid] = v2; ri[tid] = i2; }
        }
        __syncthreads();
    }
    const float mx = rv[0];
    float ls = 0.f;
    for (int v = tid; v < VV; v += 256) ls += expf(lrow[(size_t)b * VV + v] - mx);
    rs[tid] = ls;
    __syncthreads();
    for (int off = 128; off > 0; off >>= 1) {
        if (tid < off) rs[tid] += rs[tid + off];
        __syncthreads();
    }
    const float inv = 1.0f / rs[0];
    float* orow = out + ((size_t)b * NSTEPS + step) * VV;
    for (int v = tid; v < VV; v += 256) orow[v] = expf(lrow[(size_t)b * VV + v] - mx) * inv;
    if (tid == 0) y[b] = ri[0];
}

// ---------------- host launch ----------------
extern "C" void kernel_launch(void* const* d_in, const int* in_sizes, int n_in,
                              void* d_out, int out_size, void* d_ws, size_t ws_size,
                              hipStream_t stream)
{
    const int*   source  = (const int*)d_in[0];
    const float* emb_enc = (const float*)d_in[1];
    const float* Wx_e    = (const float*)d_in[2];
    const float* Wh_e    = (const float*)d_in[3];
    const float* b_e     = (const float*)d_in[4];
    const float* emb_dec = (const float*)d_in[5];
    const float* Wx_d    = (const float*)d_in[6];
    const float* Wh_d    = (const float*)d_in[7];
    const float* b_d     = (const float*)d_in[8];
    const float* W_a     = (const float*)d_in[9];
    const float* W_c     = (const float*)d_in[10];
    const float* b_c     = (const float*)d_in[11];
    const float* W_out   = (const float*)d_in[12];
    const float* b_out   = (const float*)d_in[13];
    float* out = (float*)d_out;

    // workspace layout (floats) — identical to the proven version.
    // lpart aliases zpart, lrow aliases wcpart (disjoint lifetimes).
    float* ws = (float*)d_ws;
    float* h    = ws;                    // 32768
    float* c    = h + 32768;             // 32768
    float* hs   = c + 32768;             // 2097152
    float* hs_a = hs + 2097152;          // 2097152
    float* ctxb = hs_a + 2097152;        // 32768
    float* htb  = ctxb + 32768;          // 32768
    float* zpart  = htb + 32768;         // 4194304 (also lpart)
    float* wcpart = zpart + 4194304;     // 2097152 (also lrow)
    int*   y = (int*)(wcpart + 2097152); // 32 ints
    float* lpart = zpart;
    float* lrow  = wcpart;

    MegaP pr;
    pr.source = source; pr.emb_enc = emb_enc;
    pr.Wx_e = Wx_e; pr.Wh_e = Wh_e; pr.b_e = b_e;
    pr.emb_dec = emb_dec; pr.Wx_d = Wx_d; pr.Wh_d = Wh_d; pr.b_d = b_d;
    pr.W_a = W_a; pr.W_c = W_c; pr.b_c = b_c;
    pr.W_out = W_out; pr.b_out = b_out;
    pr.out = out;
    pr.h = h; pr.c = c; pr.hs = hs; pr.hs_a = hs_a; pr.ctx = ctxb; pr.ht = htb;
    pr.zpart = zpart; pr.wcpart = wcpart; pr.y = y;

    void* args[] = { &pr };
    hipError_t err = hipLaunchCooperativeKernel(mega, dim3(GRID), dim3(256),
                                                args, 0u, stream);
    if (err == hipSuccess) return;

    // -------- fallback: proven multi-kernel path --------
    init_hc<<<128, 256, 0, stream>>>(h, c);
    for (int s = 0; s < SS; s++) {
        gemm_skinny<64><<<256, 256, 0, stream>>>(
            nullptr, h, source + s, SS, emb_enc, Wx_e, Wh_e, 1024, 4096, 8, zpart);
        enc_gates<<<128, 256, 0, stream>>>(zpart, 32, b_e, h, c, hs, s);
    }
    hsa_kernel<<<512, 256, 0, stream>>>(hs, W_a, hs_a, y);
    for (int t = 0; t < NSTEPS; t++) {
        gemm_skinny<64><<<256, 256, 0, stream>>>(
            nullptr, h, y, 1, emb_dec, Wx_d, Wh_d, 1024, 4096, 8, zpart);
        attn_gates<<<32, 256, 0, stream>>>(zpart, 32, b_d, y, h, c, hs_a, hs, source, ctxb);
        gemm_skinny<32><<<128, 256, 0, stream>>>(
            ctxb, h, nullptr, 0, nullptr, W_c, nullptr, 2048, 1024, 2, wcpart);
        ht_reduce<<<128, 256, 0, stream>>>(wcpart, 64, b_c, htb);
        gemm_skinny<256><<<252, 256, 0, stream>>>(
            htb, nullptr, nullptr, 0, nullptr, W_out, nullptr, 1024, 32000, 63, lpart);
        softmax_out<<<32, 256, 0, stream>>>(lpart, b_out, lrow, out, y, t);
    }
}